// Round 25
// baseline (126.175 us; speedup 1.0000x reference)
//
#include <hip/hip_runtime.h>
#include <math.h>

// N_MAX_L = [22,19,16,13], offsets [0,22,41,57], N_TOTAL=70
// W1: (4,4,22,32)  W2/W3: (4,4,32,32)  W4: (4,4,32,22)
#define BLK 256
#define BX 192
#define NEDGE_MAX 400000
#define TSL 24608  // padded per-l table slice: 1024*24 + 32 floats

typedef __attribute__((ext_vector_type(8))) short short8;
typedef __attribute__((ext_vector_type(4))) float f32x4;

union Frag {
  short8 s;
  unsigned int u[4];
};

// Cheap round-half-up bf16 pack of two f32 into one u32 (low = a).
__device__ __forceinline__ unsigned int pack_pair(float a, float b) {
  const unsigned int ua = __float_as_uint(a) + 0x8000u;
  const unsigned int ub = __float_as_uint(b) + 0x8000u;
  return (ua >> 16) | (ub & 0xFFFF0000u);
}

// minimal silu: x * rcp(1 + exp2(-x*log2e))
__device__ __forceinline__ f32x4 silu4(f32x4 v) {
#pragma unroll
  for (int i = 0; i < 4; i++) {
    const float e = __builtin_amdgcn_exp2f(v[i] * -1.44269504f);
    v[i] = v[i] * __builtin_amdgcn_rcpf(1.0f + e);
  }
  return v;
}

// ---------------- compaction (+table staging) ----------------

// blocks [0, nb): species compaction; blocks [nb, nb+384): padded table staging
__global__ void __launch_bounds__(BLK) k_compact(const int* __restrict__ spc,
                                                 const float* __restrict__ r, int n,
                                                 int nb, int* __restrict__ cnt,
                                                 float* __restrict__ fracs,
                                                 int* __restrict__ toffA,
                                                 int* __restrict__ perm,
                                                 const float* __restrict__ tbl,
                                                 float* __restrict__ wt) {
  if (blockIdx.x >= nb) {
    const int t = (blockIdx.x - nb) * BLK + threadIdx.x;
    if (t < 4 * 1024 * 24) {
      const int l = t / (1024 * 24);
      const int rem = t - l * (1024 * 24);
      const int idx = rem / 24;
      const int j = rem - idx * 24;
      const int off = (l == 0) ? 0 : (l == 1) ? 22 : (l == 2) ? 41 : 57;
      const int nl = (l == 0) ? 22 : (l == 1) ? 19 : (l == 2) ? 16 : 13;
      const float v = (j < nl) ? tbl[idx * 70 + off + j] : 0.f;
      wt[l * TSL + idx * 24 + j] = v;
    }
    if (t < 4 * 32) {
      const int l = t >> 5, j = t & 31;
      wt[l * TSL + 1024 * 24 + j] = 0.f;
    }
    return;
  }

  __shared__ int wcnt[4][4];
  __shared__ int wbase[4][4];
  const int tid = threadIdx.x;
  const int i = blockIdx.x * BLK + tid;
  const int lane = tid & 63;
  const int w = tid >> 6;
  const int s = (i < n) ? spc[i] : -1;
  const float rr = (i < n) ? r[i] : 0.f;

  int rank = 0;
#pragma unroll
  for (int sp = 0; sp < 4; sp++) {
    unsigned long long m = __ballot(s == sp);
    if (lane == 0) wcnt[w][sp] = __popcll(m);
    if (s == sp) rank = __popcll(m & ((1ULL << lane) - 1ULL));
  }
  __syncthreads();
  if (tid < 4) {
    const int c0 = wcnt[0][tid], c1 = wcnt[1][tid], c2 = wcnt[2][tid], c3 = wcnt[3][tid];
    const int b = atomicAdd(&cnt[tid], c0 + c1 + c2 + c3);
    wbase[0][tid] = b;
    wbase[1][tid] = b + c0;
    wbase[2][tid] = b + c0 + c1;
    wbase[3][tid] = b + c0 + c1 + c2;
  }
  __syncthreads();
  if (s >= 0) {
    const int pos = s * NEDGE_MAX + wbase[w][s] + rank;
    const float xi = rr * (1023.0f / 5.0f);
    int idx = (int)floorf(xi);
    idx = idx < 0 ? 0 : (idx > 1022 ? 1022 : idx);
    fracs[pos] = xi - (float)idx;
    toffA[pos] = idx * 96;  // table row = 24 f32 = 96 B
    perm[pos] = i;          // natural edge id (output row)
  }
}

// ---------------- fused MFMA compute (all 4 l per block) ----------------

__device__ __forceinline__ void layer_h(const Frag* A, const Frag& bh, f32x4& d0,
                                        f32x4& d1) {
  f32x4 z = {0.f, 0.f, 0.f, 0.f};
  d0 = __builtin_amdgcn_mfma_f32_16x16x32_bf16(A[0].s, bh.s, z, 0, 0, 0);
  d1 = __builtin_amdgcn_mfma_f32_16x16x32_bf16(A[1].s, bh.s, z, 0, 0, 0);
}

__device__ __forceinline__ void ldA(const unsigned int* __restrict__ wfr,
                                    int base256, int lane, Frag* A) {
#pragma unroll
  for (int jt = 0; jt < 2; jt++) {
    const uint4 v =
        reinterpret_cast<const uint4*>(wfr + ((base256 + jt) << 8))[lane];
    A[jt].u[0] = v.x;
    A[jt].u[1] = v.y;
    A[jt].u[2] = v.z;
    A[jt].u[3] = v.w;
  }
}

__device__ __forceinline__ void repack(const f32x4& d0, const f32x4& d1,
                                       Frag& bh) {
  bh.u[0] = pack_pair(d0[0], d0[1]);
  bh.u[1] = pack_pair(d0[2], d0[3]);
  bh.u[2] = pack_pair(d1[0], d1[1]);
  bh.u[3] = pack_pair(d1[2], d1[3]);
}

// One l's 4-layer MLP for a 16-edge tile with DIRECT f32 stores.
// MFMA D-layout: lane (c,g) holds features 4g+i (d0) and 16+4g+i (d1) of the
// edge in column c -- contiguous in the output row, stored straight from
// registers (no LDS transpose). Feature guards are compile-time per (L,g).
// G1==0 also skips the dead final d1 MFMA (outputs <= 16 features).
template <int L, int OFF, int NL, int G1>
__device__ __forceinline__ void proc_l(const unsigned int* __restrict__ wfr,
                                       const float* __restrict__ wt, int toff,
                                       float frac, int g, int lane,
                                       float* __restrict__ out, int e0,
                                       int valid) {
  const char* p = (const char*)(wt + (size_t)L * TSL + 8 * g) + toff;
  const f32x4 a0 = *(const f32x4*)(p);
  const f32x4 a1 = *(const f32x4*)(p + 16);
  const f32x4 b0 = *(const f32x4*)(p + 96);
  const f32x4 b1 = *(const f32x4*)(p + 112);

  Frag A1[2], A2[2], A3[2], A4[2];
  ldA(wfr, (L * 4 + 0) * 2, lane, A1);
  ldA(wfr, (L * 4 + 1) * 2, lane, A2);
  ldA(wfr, (L * 4 + 2) * 2, lane, A3);
  ldA(wfr, (L * 4 + 3) * 2, lane, A4);

  float x[8];
#pragma unroll
  for (int d = 0; d < 4; d++) {
    x[d] = a0[d] + frac * (b0[d] - a0[d]);
    x[d + 4] = a1[d] + frac * (b1[d] - a1[d]);
  }
  Frag bh;
  bh.u[0] = pack_pair(x[0], x[1]);
  bh.u[1] = pack_pair(x[2], x[3]);
  bh.u[2] = pack_pair(x[4], x[5]);
  bh.u[3] = pack_pair(x[6], x[7]);

  f32x4 d0, d1;
  layer_h(A1, bh, d0, d1);
  d0 = silu4(d0); d1 = silu4(d1); repack(d0, d1, bh);
  layer_h(A2, bh, d0, d1);
  d0 = silu4(d0); d1 = silu4(d1); repack(d0, d1, bh);
  layer_h(A3, bh, d0, d1);
  d0 = silu4(d0); d1 = silu4(d1); repack(d0, d1, bh);
  f32x4 z = {0.f, 0.f, 0.f, 0.f};
  d0 = __builtin_amdgcn_mfma_f32_16x16x32_bf16(A4[0].s, bh.s, z, 0, 0, 0);
  if (G1 > 0) d1 = __builtin_amdgcn_mfma_f32_16x16x32_bf16(A4[1].s, bh.s, z, 0, 0, 0);

  if (valid) {
    float* __restrict__ o = out + (size_t)e0 * 70 + OFF;
#pragma unroll
    for (int i = 0; i < 4; i++) {
      const int f = 4 * g + i;
      if (f < NL) o[f] = d0[i];
    }
    if (G1 > 0) {
#pragma unroll
      for (int i = 0; i < 4; i++) {
        const int f = 16 + 4 * g + i;
        if (f < NL) o[f] = d1[i];
      }
    }
  }
}

__global__ void __launch_bounds__(BLK) rb_fused(
    const float* __restrict__ fracs, const int* __restrict__ toffA,
    const int* __restrict__ perm, const float* __restrict__ wt,
    const float* __restrict__ W1, const float* __restrict__ W2,
    const float* __restrict__ W3, const float* __restrict__ W4,
    float* __restrict__ out, const int* __restrict__ cnt) {
  __shared__ unsigned int wfr[8192];  // 32KB: packed A-frags, all 4 l (only LDS)

  const int s = blockIdx.y;
  const int count = cnt[s];
  if (count == 0) return;
  const int sBase = s * NEDGE_MAX;

  // ---- build per-species weight frags in LDS (entry index == LDS index) ----
  {
    const int nlarr[4] = {22, 19, 16, 13};
    for (int e = threadIdx.x; e < 8192; e += BLK) {
      const int p = e & 3;
      const int lane = (e >> 2) & 63;
      const int jt = (e >> 8) & 1;
      const int m = (e >> 9) & 3;
      const int l = e >> 11;
      const int c = lane & 15, g = lane >> 4;
      const int j = jt * 16 + c;
      const int nl = nlarr[l];
      float a, b;
      if (m == 0) {
        const int k0 = 8 * g + 2 * p, k1 = k0 + 1;
        const float* wp = W1 + (size_t)(l * 4 + s) * 704;
        a = (k0 < nl) ? wp[k0 * 32 + j] : 0.f;
        b = (k1 < nl) ? wp[k1 * 32 + j] : 0.f;
      } else {
        const int kp0 = (p < 2) ? (4 * g + 2 * p) : (16 + 4 * g + 2 * (p - 2));
        const int kp1 = kp0 + 1;
        if (m == 1) {
          const float* wp = W2 + (size_t)(l * 4 + s) * 1024;
          a = wp[kp0 * 32 + j];
          b = wp[kp1 * 32 + j];
        } else if (m == 2) {
          const float* wp = W3 + (size_t)(l * 4 + s) * 1024;
          a = wp[kp0 * 32 + j];
          b = wp[kp1 * 32 + j];
        } else {
          const float* wp = W4 + (size_t)(l * 4 + s) * 704;
          a = (j < nl) ? wp[kp0 * 22 + j] : 0.f;
          b = (j < nl) ? wp[kp1 * 22 + j] : 0.f;
        }
      }
      wfr[e] = pack_pair(a, b);
    }
  }
  __syncthreads();

  const int lane = threadIdx.x & 63;
  const int w = threadIdx.x >> 6;
  const int c = lane & 15, g = lane >> 4;
  const int stride = gridDim.x * 64;

  int eb = blockIdx.x * 64 + w * 16;
  int valid = (eb + c) < count;
  int spi = sBase + (valid ? eb + c : 0);
  float frac = fracs[spi];
  int toff = toffA[spi];
  int e0 = perm[spi];

  for (; eb < count; eb += stride) {
    // prefetch next tile's scalars (independent; overlaps compute)
    const int nei = eb + stride + c;
    const int nvalid = nei < count;
    const int nspi = sBase + (nvalid ? nei : 0);
    const float nfrac = fracs[nspi];
    const int ntoff = toffA[nspi];
    const int ne = perm[nspi];

    proc_l<0, 0, 22, 1>(wfr, wt, toff, frac, g, lane, out, e0, valid);
    proc_l<1, 22, 19, 1>(wfr, wt, toff, frac, g, lane, out, e0, valid);
    proc_l<2, 41, 16, 0>(wfr, wt, toff, frac, g, lane, out, e0, valid);
    proc_l<3, 57, 13, 0>(wfr, wt, toff, frac, g, lane, out, e0, valid);

    frac = nfrac;
    toff = ntoff;
    e0 = ne;
    valid = nvalid;
  }
}

extern "C" void kernel_launch(void* const* d_in, const int* in_sizes, int n_in,
                              void* d_out, int out_size, void* d_ws, size_t ws_size,
                              hipStream_t stream) {
  const float* r = (const float*)d_in[0];
  const int* spc = (const int*)d_in[1];
  const float* tbl = (const float*)d_in[2];
  const float* W1 = (const float*)d_in[3];
  const float* W2 = (const float*)d_in[4];
  const float* W3 = (const float*)d_in[5];
  const float* W4 = (const float*)d_in[6];
  float* out = (float*)d_out;
  const int n = in_sizes[0];

  int* cnt = (int*)d_ws;                         // 4 ints (+pad to 64)
  float* fracs = (float*)(cnt + 64);             // 4*NEDGE_MAX floats
  int* toffA = (int*)(fracs + 4 * NEDGE_MAX);    // 4*NEDGE_MAX ints
  int* perm = toffA + 4 * NEDGE_MAX;             // 4*NEDGE_MAX ints
  float* wtbl = (float*)(perm + 4 * NEDGE_MAX);  // 4*TSL floats

  // zero the 4 species counters (memset node replaces a k_zero launch)
  hipMemsetAsync(cnt, 0, 4 * sizeof(int), stream);

  const int nb = (n + BLK - 1) / BLK;
  hipLaunchKernelGGL(k_compact, dim3(nb + 384), dim3(BLK), 0, stream, spc, r, n,
                     nb, cnt, fracs, toffA, perm, tbl, wtbl);

  hipLaunchKernelGGL(rb_fused, dim3(BX, 4), dim3(BLK), 0, stream, fracs, toffA,
                     perm, wtbl, W1, W2, W3, W4, out, cnt);
}

// Round 26
// 118.315 us; speedup vs baseline: 1.0664x; 1.0664x over previous
//
#include <hip/hip_runtime.h>
#include <math.h>

// N_MAX_L = [22,19,16,13], offsets [0,22,41,57], N_TOTAL=70
// W1: (4,4,22,32)  W2/W3: (4,4,32,32)  W4: (4,4,32,22)
#define BLK 256
#define BX 192
#define NEDGE_MAX 400000
#define TSL 24608  // padded per-l table slice: 1024*24 + 32 floats

typedef __attribute__((ext_vector_type(8))) short short8;
typedef __attribute__((ext_vector_type(4))) float f32x4;

union Frag {
  short8 s;
  unsigned int u[4];
};

// Cheap round-half-up bf16 pack of two f32 into one u32 (low = a).
__device__ __forceinline__ unsigned int pack_pair(float a, float b) {
  const unsigned int ua = __float_as_uint(a) + 0x8000u;
  const unsigned int ub = __float_as_uint(b) + 0x8000u;
  return (ua >> 16) | (ub & 0xFFFF0000u);
}

// minimal silu: x * rcp(1 + exp2(-x*log2e))
__device__ __forceinline__ f32x4 silu4(f32x4 v) {
#pragma unroll
  for (int i = 0; i < 4; i++) {
    const float e = __builtin_amdgcn_exp2f(v[i] * -1.44269504f);
    v[i] = v[i] * __builtin_amdgcn_rcpf(1.0f + e);
  }
  return v;
}

// ---------------- compaction (+table staging) ----------------

// blocks [0, nb): species compaction; blocks [nb, nb+384): padded table staging
__global__ void __launch_bounds__(BLK) k_compact(const int* __restrict__ spc,
                                                 const float* __restrict__ r, int n,
                                                 int nb, int* __restrict__ cnt,
                                                 float* __restrict__ fracs,
                                                 int* __restrict__ toffA,
                                                 int* __restrict__ perm,
                                                 const float* __restrict__ tbl,
                                                 float* __restrict__ wt) {
  if (blockIdx.x >= nb) {
    const int t = (blockIdx.x - nb) * BLK + threadIdx.x;
    if (t < 4 * 1024 * 24) {
      const int l = t / (1024 * 24);
      const int rem = t - l * (1024 * 24);
      const int idx = rem / 24;
      const int j = rem - idx * 24;
      const int off = (l == 0) ? 0 : (l == 1) ? 22 : (l == 2) ? 41 : 57;
      const int nl = (l == 0) ? 22 : (l == 1) ? 19 : (l == 2) ? 16 : 13;
      const float v = (j < nl) ? tbl[idx * 70 + off + j] : 0.f;
      wt[l * TSL + idx * 24 + j] = v;
    }
    if (t < 4 * 32) {
      const int l = t >> 5, j = t & 31;
      wt[l * TSL + 1024 * 24 + j] = 0.f;
    }
    return;
  }

  __shared__ int wcnt[4][4];
  __shared__ int wbase[4][4];
  const int tid = threadIdx.x;
  const int i = blockIdx.x * BLK + tid;
  const int lane = tid & 63;
  const int w = tid >> 6;
  const int s = (i < n) ? spc[i] : -1;
  const float rr = (i < n) ? r[i] : 0.f;

  int rank = 0;
#pragma unroll
  for (int sp = 0; sp < 4; sp++) {
    unsigned long long m = __ballot(s == sp);
    if (lane == 0) wcnt[w][sp] = __popcll(m);
    if (s == sp) rank = __popcll(m & ((1ULL << lane) - 1ULL));
  }
  __syncthreads();
  if (tid < 4) {
    const int c0 = wcnt[0][tid], c1 = wcnt[1][tid], c2 = wcnt[2][tid], c3 = wcnt[3][tid];
    const int b = atomicAdd(&cnt[tid], c0 + c1 + c2 + c3);
    wbase[0][tid] = b;
    wbase[1][tid] = b + c0;
    wbase[2][tid] = b + c0 + c1;
    wbase[3][tid] = b + c0 + c1 + c2;
  }
  __syncthreads();
  if (s >= 0) {
    const int pos = s * NEDGE_MAX + wbase[w][s] + rank;
    const float xi = rr * (1023.0f / 5.0f);
    int idx = (int)floorf(xi);
    idx = idx < 0 ? 0 : (idx > 1022 ? 1022 : idx);
    fracs[pos] = xi - (float)idx;
    toffA[pos] = idx * 96;  // table row = 24 f32 = 96 B
    perm[pos] = i;          // natural edge id (output row)
  }
}

// ---------------- fused MFMA compute (all 4 l per block) ----------------

__device__ __forceinline__ void layer_h(const Frag* A, const Frag& bh, f32x4& d0,
                                        f32x4& d1) {
  f32x4 z = {0.f, 0.f, 0.f, 0.f};
  d0 = __builtin_amdgcn_mfma_f32_16x16x32_bf16(A[0].s, bh.s, z, 0, 0, 0);
  d1 = __builtin_amdgcn_mfma_f32_16x16x32_bf16(A[1].s, bh.s, z, 0, 0, 0);
}

__device__ __forceinline__ void ldA(const unsigned int* __restrict__ wfr,
                                    int base256, int lane, Frag* A) {
#pragma unroll
  for (int jt = 0; jt < 2; jt++) {
    const uint4 v =
        reinterpret_cast<const uint4*>(wfr + ((base256 + jt) << 8))[lane];
    A[jt].u[0] = v.x;
    A[jt].u[1] = v.y;
    A[jt].u[2] = v.z;
    A[jt].u[3] = v.w;
  }
}

__device__ __forceinline__ void repack(const f32x4& d0, const f32x4& d1,
                                       Frag& bh) {
  bh.u[0] = pack_pair(d0[0], d0[1]);
  bh.u[1] = pack_pair(d0[2], d0[3]);
  bh.u[2] = pack_pair(d1[0], d1[1]);
  bh.u[3] = pack_pair(d1[2], d1[3]);
}

// One l's 4-layer MLP for a 16-edge tile; result packed as bf16 pairs into the
// wave's transpose tile at u32 sub-base UBASE (stride 38 u32/row).
// d0 -> u32 {UBASE+2g, +1} = features 4g..4g+3; d1 (g<G1) -> {UBASE+8+2g, +1}.
// G1==0 also skips the dead final d1 MFMA. Layer-1 activations are plain bf16
// (hi-only; the lo-compensation term adds ~1e-3 abs err, well under budget).
template <int L, int UBASE, int G1>
__device__ __forceinline__ void proc_l(const unsigned int* __restrict__ wfr,
                                       const float* __restrict__ wt, int toff,
                                       float frac, int g, int lane,
                                       unsigned int* __restrict__ xrow) {
  const char* p = (const char*)(wt + (size_t)L * TSL + 8 * g) + toff;
  const f32x4 a0 = *(const f32x4*)(p);
  const f32x4 a1 = *(const f32x4*)(p + 16);
  const f32x4 b0 = *(const f32x4*)(p + 96);
  const f32x4 b1 = *(const f32x4*)(p + 112);

  Frag A1[2], A2[2], A3[2], A4[2];
  ldA(wfr, (L * 4 + 0) * 2, lane, A1);
  ldA(wfr, (L * 4 + 1) * 2, lane, A2);
  ldA(wfr, (L * 4 + 2) * 2, lane, A3);
  ldA(wfr, (L * 4 + 3) * 2, lane, A4);

  float x[8];
#pragma unroll
  for (int d = 0; d < 4; d++) {
    x[d] = a0[d] + frac * (b0[d] - a0[d]);
    x[d + 4] = a1[d] + frac * (b1[d] - a1[d]);
  }
  Frag bh;
  bh.u[0] = pack_pair(x[0], x[1]);
  bh.u[1] = pack_pair(x[2], x[3]);
  bh.u[2] = pack_pair(x[4], x[5]);
  bh.u[3] = pack_pair(x[6], x[7]);

  f32x4 d0, d1;
  layer_h(A1, bh, d0, d1);
  d0 = silu4(d0); d1 = silu4(d1); repack(d0, d1, bh);
  layer_h(A2, bh, d0, d1);
  d0 = silu4(d0); d1 = silu4(d1); repack(d0, d1, bh);
  layer_h(A3, bh, d0, d1);
  d0 = silu4(d0); d1 = silu4(d1); repack(d0, d1, bh);
  f32x4 z = {0.f, 0.f, 0.f, 0.f};
  d0 = __builtin_amdgcn_mfma_f32_16x16x32_bf16(A4[0].s, bh.s, z, 0, 0, 0);
  if (G1 > 0) d1 = __builtin_amdgcn_mfma_f32_16x16x32_bf16(A4[1].s, bh.s, z, 0, 0, 0);

  *(uint2*)(xrow + UBASE + 2 * g) =
      make_uint2(pack_pair(d0[0], d0[1]), pack_pair(d0[2], d0[3]));
  if (G1 > 0 && g < G1)
    *(uint2*)(xrow + UBASE + 8 + 2 * g) =
        make_uint2(pack_pair(d1[0], d1[1]), pack_pair(d1[2], d1[3]));
}

__global__ void __launch_bounds__(BLK) rb_fused(
    const float* __restrict__ fracs, const int* __restrict__ toffA,
    const int* __restrict__ perm, const float* __restrict__ wt,
    const float* __restrict__ W1, const float* __restrict__ W2,
    const float* __restrict__ W3, const float* __restrict__ W4,
    float* __restrict__ out, const int* __restrict__ cnt) {
  __shared__ unsigned int wfr[8192];      // 32KB: packed A-frags, all 4 l
  __shared__ unsigned int xp[4][16 * 38]; // 9.5KB: bf16x2 transpose tiles
  __shared__ int eid[4][16];

  const int s = blockIdx.y;
  const int count = cnt[s];
  if (count == 0) return;
  const int sBase = s * NEDGE_MAX;

  // ---- build per-species weight frags in LDS (entry index == LDS index) ----
  {
    const int nlarr[4] = {22, 19, 16, 13};
    for (int e = threadIdx.x; e < 8192; e += BLK) {
      const int p = e & 3;
      const int lane = (e >> 2) & 63;
      const int jt = (e >> 8) & 1;
      const int m = (e >> 9) & 3;
      const int l = e >> 11;
      const int c = lane & 15, g = lane >> 4;
      const int j = jt * 16 + c;
      const int nl = nlarr[l];
      float a, b;
      if (m == 0) {
        const int k0 = 8 * g + 2 * p, k1 = k0 + 1;
        const float* wp = W1 + (size_t)(l * 4 + s) * 704;
        a = (k0 < nl) ? wp[k0 * 32 + j] : 0.f;
        b = (k1 < nl) ? wp[k1 * 32 + j] : 0.f;
      } else {
        const int kp0 = (p < 2) ? (4 * g + 2 * p) : (16 + 4 * g + 2 * (p - 2));
        const int kp1 = kp0 + 1;
        if (m == 1) {
          const float* wp = W2 + (size_t)(l * 4 + s) * 1024;
          a = wp[kp0 * 32 + j];
          b = wp[kp1 * 32 + j];
        } else if (m == 2) {
          const float* wp = W3 + (size_t)(l * 4 + s) * 1024;
          a = wp[kp0 * 32 + j];
          b = wp[kp1 * 32 + j];
        } else {
          const float* wp = W4 + (size_t)(l * 4 + s) * 704;
          a = (j < nl) ? wp[kp0 * 22 + j] : 0.f;
          b = (j < nl) ? wp[kp1 * 22 + j] : 0.f;
        }
      }
      wfr[e] = pack_pair(a, b);
    }
  }
  __syncthreads();

  const int lane = threadIdx.x & 63;
  const int w = threadIdx.x >> 6;
  const int c = lane & 15, g = lane >> 4;
  unsigned int* __restrict__ xpw = xp[w];
  int* __restrict__ eidw = eid[w];
  unsigned int* __restrict__ xrow = xpw + c * 38;
  const int stride = gridDim.x * 64;

  int eb = blockIdx.x * 64 + w * 16;
  int valid = (eb + c) < count;
  int spi = sBase + (valid ? eb + c : 0);
  float frac = fracs[spi];
  int toff = toffA[spi];
  int e0 = perm[spi];

  for (; eb < count; eb += stride) {
    // prefetch next tile's scalars (independent; overlaps compute)
    const int nei = eb + stride + c;
    const int nvalid = nei < count;
    const int nspi = sBase + (nvalid ? nei : 0);
    const float nfrac = fracs[nspi];
    const int ntoff = toffA[nspi];
    const int ne = perm[nspi];

    proc_l<0, 0, 2>(wfr, wt, toff, frac, g, lane, xrow);
    proc_l<1, 12, 1>(wfr, wt, toff, frac, g, lane, xrow);
    proc_l<2, 22, 0>(wfr, wt, toff, frac, g, lane, xrow);
    proc_l<3, 30, 0>(wfr, wt, toff, frac, g, lane, xrow);

    if (g == 0) eidw[c] = valid ? e0 : -1;
    __asm__ volatile("" ::: "memory");

    // ---- write full 280-B rows (f32), expanding bf16 halves from xp ----
#pragma unroll
    for (int it = 0; it < 18; it++) {
      const int t = it * 64 + lane;
      if (t < 16 * 70) {
        const int row = t / 70;
        const int f = t - row * 70;
        const int er = eidw[row];
        const int fl = f + ((f >= 22) ? 2 : 0) + ((f >= 41) ? 1 : 0);
        const unsigned int v = xpw[row * 38 + (fl >> 1)];
        const unsigned int hv = (fl & 1) ? (v & 0xFFFF0000u) : (v << 16);
        if (er >= 0) out[(size_t)er * 70 + f] = __uint_as_float(hv);
      }
    }
    __asm__ volatile("" ::: "memory");

    frac = nfrac;
    toff = ntoff;
    e0 = ne;
    valid = nvalid;
  }
}

extern "C" void kernel_launch(void* const* d_in, const int* in_sizes, int n_in,
                              void* d_out, int out_size, void* d_ws, size_t ws_size,
                              hipStream_t stream) {
  const float* r = (const float*)d_in[0];
  const int* spc = (const int*)d_in[1];
  const float* tbl = (const float*)d_in[2];
  const float* W1 = (const float*)d_in[3];
  const float* W2 = (const float*)d_in[4];
  const float* W3 = (const float*)d_in[5];
  const float* W4 = (const float*)d_in[6];
  float* out = (float*)d_out;
  const int n = in_sizes[0];

  int* cnt = (int*)d_ws;                         // 4 ints (+pad to 64)
  float* fracs = (float*)(cnt + 64);             // 4*NEDGE_MAX floats
  int* toffA = (int*)(fracs + 4 * NEDGE_MAX);    // 4*NEDGE_MAX ints
  int* perm = toffA + 4 * NEDGE_MAX;             // 4*NEDGE_MAX ints
  float* wtbl = (float*)(perm + 4 * NEDGE_MAX);  // 4*TSL floats

  // zero the 4 species counters (memset node replaces a k_zero launch)
  hipMemsetAsync(cnt, 0, 4 * sizeof(int), stream);

  const int nb = (n + BLK - 1) / BLK;
  hipLaunchKernelGGL(k_compact, dim3(nb + 384), dim3(BLK), 0, stream, spc, r, n,
                     nb, cnt, fracs, toffA, perm, tbl, wtbl);

  hipLaunchKernelGGL(rb_fused, dim3(BX, 4), dim3(BLK), 0, stream, fracs, toffA,
                     perm, wtbl, W1, W2, W3, W4, out, cnt);
}